// Round 6
// baseline (278.733 us; speedup 1.0000x reference)
//
#include <hip/hip_runtime.h>
#include <hip/hip_bf16.h>

typedef __attribute__((ext_vector_type(8))) short short8;
typedef __attribute__((ext_vector_type(4))) float f32x4;
typedef __attribute__((ext_vector_type(4))) int   i32x4;

#define NTOP 1000
#define KC   256
#define MROWS 40000

static __device__ __forceinline__ unsigned short f2bf(float x) {
    union { float f; unsigned u; } v; v.f = x;
    unsigned r = (v.u + 0x7FFFu + ((v.u >> 16) & 1u)) >> 16;
    return (unsigned short)r;
}

// Kernel 1: colsum[j] += sum over an 8-row slab of nw. colsum pre-zeroed by memset.
__global__ void k_prep(const float* __restrict__ nw,
                       float* __restrict__ colsum) {
    int j  = blockIdx.x * 256 + threadIdx.x;
    int i0 = blockIdx.y * 8;
    if (j < NTOP) {
        float s = 0.f;
        int iend = min(i0 + 8, NTOP);
        for (int i = i0; i < iend; ++i) s += nw[(size_t)i * NTOP + j];
        atomicAdd(colsum + j, s);
    }
}

// Kernel 2: build B' in MFMA-fragment order:
//   B'[((nt*8 + s)*64 + lane)] (short8) = V_j[n = nt*16 + (lane&15),
//                                             k = s*32 + (lane>>4)*8 + j]
__global__ void k_vj(const float* __restrict__ V,
                     const float* __restrict__ noise,
                     const float* __restrict__ colsum,
                     unsigned short* __restrict__ Bp) {
    int t  = blockIdx.x * 256 + threadIdx.x;   // 0 .. 64*8*64-1 = 32767
    int nt = t >> 9;
    int s  = (t >> 6) & 7;
    int l  = t & 63;
    int lm = l & 15, lq = l >> 4;
    int n  = nt * 16 + lm;
    int k0 = s * 32 + lq * 8;
    union { short8 v; unsigned short us[8]; } pk;
    if (n < NTOP) {
        float cs = colsum[n];
        #pragma unroll
        for (int j = 0; j < 8; ++j) {
            int idx = n * KC + k0 + j;
            pk.us[j] = f2bf(V[idx] * cs + 0.1f * noise[idx]);
        }
    } else {
        #pragma unroll
        for (int j = 0; j < 8; ++j) pk.us[j] = 0;
    }
    reinterpret_cast<short8*>(Bp)[t] = pk.v;
}

// Kernel 3: fused U_emb + GEMM + sigmoid + masked Normal log-prob + reduce.
// SWAPPED MFMA OPERANDS: acc = mfma(bfr, afr, acc) puts m in lanes (col=lane&15)
// and n in regs (row=lq*4+r) -> each lane owns 4 CONSECUTIVE n at fixed m, so
// R and C load as dwordx4 (4x fewer epilogue instructions; 64B-contig per row).
// R/C still software-pipelined one iteration ahead with pinned issue slots.
__global__ __launch_bounds__(256, 6) void k_main(
    const float* __restrict__ U, const float* __restrict__ w5,
    const float* __restrict__ b1, const short8* __restrict__ Bf,
    const float* __restrict__ R, const int* __restrict__ C,
    float* __restrict__ out)
{
    __shared__ short8 Alds[512];   // 8 s-steps x 64 lanes, 8 KB

    const int tid  = threadIdx.x;
    const int wave = tid >> 6;
    const int l    = tid & 63;
    const int lm = l & 15;       // now: output m within tile
    const int lq = l >> 4;       // quad: selects n-subblock of 4
    const int m0 = blockIdx.x << 4;

    const float w0 = w5[0], w1 = w5[1], w2 = w5[2], w3 = w5[3], w4 = w5[4];
    const float bb = b1[0];

    // ---- Cooperative A-fragment build: 512 chunks, 2 per thread ----
    #pragma unroll
    for (int o = tid; o < 512; o += 256) {
        const int ll = o & 63;
        const int s  = o >> 6;
        const int m  = m0 + (ll & 15);
        const int k0 = (s << 5) + ((ll >> 4) << 3);
        const f32x4* up4 = reinterpret_cast<const f32x4*>(
            U + ((size_t)m * KC + k0) * 5);
        float u[40];
        #pragma unroll
        for (int i = 0; i < 10; ++i) {
            f32x4 t = up4[i];
            u[i*4+0] = t.x; u[i*4+1] = t.y; u[i*4+2] = t.z; u[i*4+3] = t.w;
        }
        union { short8 v; unsigned short us[8]; } pk;
        #pragma unroll
        for (int j = 0; j < 8; ++j) {
            float e = u[j*5+0]*w0 + u[j*5+1]*w1 + u[j*5+2]*w2
                    + u[j*5+3]*w3 + u[j*5+4]*w4 + bb;
            pk.us[j] = f2bf(e);
        }
        Alds[o] = pk.v;
    }
    __syncthreads();

    // Per-lane row base: m = m0 + lm is FIXED for this lane now.
    const size_t rbase = (size_t)(m0 + lm) * NTOP;

    // Load two 16-col n-tiles (t0, t0+1) of an iteration's R/C as dwordx4.
    auto LOADH = [&](int ns_, int t0, f32x4* rv4, i32x4* cv4) {
        #pragma unroll
        for (int tt = 0; tt < 2; ++tt) {
            const int nst = (ns_ << 6) + ((t0 + tt) << 4) + (lq << 2);
            if (nst < NTOP) {
                rv4[tt] = *reinterpret_cast<const f32x4*>(R + rbase + nst);
                cv4[tt] = *reinterpret_cast<const i32x4*>(C + rbase + nst);
            } else {
                rv4[tt] = (f32x4){0.f, 0.f, 0.f, 0.f};
                cv4[tt] = (i32x4){0, 0, 0, 0};
            }
        }
    };

    float lpsum = 0.f;

    // Consume one half: tiles (t0, t0+1). acc row r -> n = ns*64 + t*16 + lq*4 + r.
    auto EPI = [&](const f32x4& a0, const f32x4& a1,
                   const f32x4* rv4, const i32x4* cv4) {
        #pragma unroll
        for (int tt = 0; tt < 2; ++tt) {
            const f32x4 a = tt ? a1 : a0;
            #pragma unroll
            for (int r = 0; r < 4; ++r) {
                float muv = 1.f / (1.f + __expf(-a[r]));
                float d   = rv4[tt][r] - muv;
                float lp  = -50.f * d * d + 1.3836465597893728f;
                if (cv4[tt][r] == 1) lpsum += lp;
            }
        }
    };

    const int ns0 = wave << 2;

    f32x4 rA[2], rB[2]; i32x4 cA[2], cB[2];
    LOADH(ns0, 0, rA, cA);     // prologue: first iteration unpipelined
    LOADH(ns0, 2, rB, cB);

    #pragma unroll
    for (int it = 0; it < 4; ++it) {
        const int ns = ns0 + it;

        f32x4 acc[4];
        #pragma unroll
        for (int t = 0; t < 4; ++t) acc[t] = (f32x4){0.f, 0.f, 0.f, 0.f};

        #pragma unroll
        for (int s = 0; s < 8; ++s) {
            const short8 afr = Alds[(s << 6) + l];
            #pragma unroll
            for (int t = 0; t < 4; ++t) {
                const short8 bfr = Bf[(((ns * 4 + t) * 8 + s) << 6) + l];
                // SWAPPED: bfr supplies rows (n), afr supplies cols (m)
                acc[t] = __builtin_amdgcn_mfma_f32_16x16x32_bf16(bfr, afr, acc[t], 0, 0, 0);
            }
        }

        f32x4 rA2[2], rB2[2]; i32x4 cA2[2], cB2[2];

        // ---- pinned issue slot: next-iter half A (after this iter's Bf loads) ----
        __builtin_amdgcn_sched_barrier(0);
        if (it < 3) LOADH(ns + 1, 0, rA2, cA2);
        __builtin_amdgcn_sched_barrier(0);

        EPI(acc[0], acc[1], rA, cA);

        // ---- pinned issue slot: next-iter half B ----
        __builtin_amdgcn_sched_barrier(0);
        if (it < 3) LOADH(ns + 1, 2, rB2, cB2);
        __builtin_amdgcn_sched_barrier(0);

        EPI(acc[2], acc[3], rB, cB);

        if (it < 3) {
            rA[0] = rA2[0]; rA[1] = rA2[1]; cA[0] = cA2[0]; cA[1] = cA2[1];
            rB[0] = rB2[0]; rB[1] = rB2[1]; cB[0] = cB2[0]; cB[1] = cB2[1];
        }
    }

    #pragma unroll
    for (int off = 32; off > 0; off >>= 1) lpsum += __shfl_down(lpsum, off);
    if (l == 0) atomicAdd(out, lpsum);
}

extern "C" void kernel_launch(void* const* d_in, const int* in_sizes, int n_in,
                              void* d_out, int out_size, void* d_ws, size_t ws_size,
                              hipStream_t stream) {
    const float* V     = (const float*)d_in[1];
    const float* R     = (const float*)d_in[2];
    const float* nw    = (const float*)d_in[3];
    const float* U     = (const float*)d_in[4];
    const float* w5    = (const float*)d_in[5];
    const float* b1    = (const float*)d_in[6];
    const float* noise = (const float*)d_in[7];
    const int*   C     = (const int*)d_in[8];
    float* out = (float*)d_out;

    // Workspace (known-safe 532,480 B footprint):
    //   colsum: [0, 4000)      (padded to 8192)
    //   Bp    : [8192, 532480) 1024*256*2 = 524288 B
    float*          colsum = (float*)d_ws;
    unsigned short* Bp     = (unsigned short*)((char*)d_ws + 8192);

    hipMemsetAsync(colsum, 0, NTOP * sizeof(float), stream);
    hipMemsetAsync(out, 0, sizeof(float), stream);
    hipLaunchKernelGGL(k_prep, dim3(4, 125), dim3(256), 0, stream, nw, colsum);
    hipLaunchKernelGGL(k_vj, dim3(128), dim3(256), 0, stream,
                       V, noise, colsum, Bp);
    hipLaunchKernelGGL(k_main, dim3(MROWS / 16), dim3(256), 0, stream,
                       U, w5, b1, (const short8*)Bp, R, C, out);
}

// Round 7
// 218.848 us; speedup vs baseline: 1.2736x; 1.2736x over previous
//
#include <hip/hip_runtime.h>
#include <hip/hip_bf16.h>

typedef __attribute__((ext_vector_type(8))) short short8;
typedef __attribute__((ext_vector_type(4))) float f32x4;
typedef __attribute__((ext_vector_type(4))) int   i32x4;

#define NTOP 1000
#define KC   256
#define MROWS 40000
#define MBLK  64

static __device__ __forceinline__ unsigned short f2bf(float x) {
    union { float f; unsigned u; } v; v.f = x;
    unsigned r = (v.u + 0x7FFFu + ((v.u >> 16) & 1u)) >> 16;
    return (unsigned short)r;
}

// Kernel 1: colsum[j] += sum over an 8-row slab of nw. colsum pre-zeroed by memset.
__global__ void k_prep(const float* __restrict__ nw,
                       float* __restrict__ colsum) {
    int j  = blockIdx.x * 256 + threadIdx.x;
    int i0 = blockIdx.y * 8;
    if (j < NTOP) {
        float s = 0.f;
        int iend = min(i0 + 8, NTOP);
        for (int i = i0; i < iend; ++i) s += nw[(size_t)i * NTOP + j];
        atomicAdd(colsum + j, s);
    }
}

// Kernel 2: build B' in MFMA-fragment order:
//   B'[((nt*8 + s)*64 + lane)] (short8) = V_j[n = nt*16 + (lane&15),
//                                             k = s*32 + (lane>>4)*8 + j]
__global__ void k_vj(const float* __restrict__ V,
                     const float* __restrict__ noise,
                     const float* __restrict__ colsum,
                     unsigned short* __restrict__ Bp) {
    int t  = blockIdx.x * 256 + threadIdx.x;   // 0 .. 64*8*64-1 = 32767
    int nt = t >> 9;
    int s  = (t >> 6) & 7;
    int l  = t & 63;
    int lm = l & 15, lq = l >> 4;
    int n  = nt * 16 + lm;
    int k0 = s * 32 + lq * 8;
    union { short8 v; unsigned short us[8]; } pk;
    if (n < NTOP) {
        float cs = colsum[n];
        #pragma unroll
        for (int j = 0; j < 8; ++j) {
            int idx = n * KC + k0 + j;
            pk.us[j] = f2bf(V[idx] * cs + 0.1f * noise[idx]);
        }
    } else {
        #pragma unroll
        for (int j = 0; j < 8; ++j) pk.us[j] = 0;
    }
    reinterpret_cast<short8*>(Bp)[t] = pk.v;
}

// Kernel 3: 64-row blocks. Each Bf fragment load feeds 4 MFMAs (4 m-tiles):
// Bf cacheline traffic drops 4x vs 16-row blocks (TCP-bound regime, round-5/6
// evidence: cache-hot replay same speed as cold -> line-request bound).
// A-build: coalesced global->LDS bounce (4 rows raw = 20KB), fragments computed
// from LDS, stored to LDS (32KB). Main loop barrier-free.
__global__ __launch_bounds__(256, 3) void k_main(
    const float* __restrict__ U, const float* __restrict__ w5,
    const float* __restrict__ b1, const short8* __restrict__ Bf,
    const float* __restrict__ R, const int* __restrict__ C,
    float* __restrict__ out)
{
    __shared__ short8 Afrag[4][8][64];   // [mt][s][ll] : 32 KB
    __shared__ float  rawU[5120];        // 4 U-rows    : 20 KB

    const int tid  = threadIdx.x;
    const int wave = tid >> 6;
    const int l    = tid & 63;
    const int lm = l & 15;       // output m within 16-tile (col = lane&15)
    const int lq = l >> 4;       // quad: n-subblock of 4 (row = lq*4 + r)
    const int m0 = blockIdx.x * MBLK;

    const float w0 = w5[0], w1 = w5[1], w2 = w5[2], w3 = w5[3], w4 = w5[4];
    const float bb = b1[0];

    // ---- A-build: 16 groups of 4 rows. Stage coalesced, compute from LDS. ----
    const float* ub = U + (size_t)m0 * (KC * 5);
    for (int g = 0; g < 16; ++g) {
        // stage rows m0+g*4 .. +4 (5120 floats, coalesced dwordx4)
        const float* src = ub + (size_t)g * 5120;
        #pragma unroll
        for (int j = 0; j < 5; ++j) {
            const int idx = j * 1024 + tid * 4;
            *reinterpret_cast<f32x4*>(&rawU[idx]) =
                *reinterpret_cast<const f32x4*>(src + idx);
        }
        __syncthreads();
        if (tid < 128) {   // 128 fragment-chunks for these 4 rows
            const int s   = tid >> 4;
            const int lqc = (tid >> 2) & 3;
            const int lmh = tid & 3;
            const int fi  = lmh * 1280 + s * 160 + lqc * 40;
            float u[40];
            #pragma unroll
            for (int i = 0; i < 10; ++i) {
                f32x4 t = *reinterpret_cast<const f32x4*>(&rawU[fi + i * 4]);
                u[i*4+0] = t.x; u[i*4+1] = t.y; u[i*4+2] = t.z; u[i*4+3] = t.w;
            }
            union { short8 v; unsigned short us[8]; } pk;
            #pragma unroll
            for (int j = 0; j < 8; ++j) {
                float e = u[j*5+0]*w0 + u[j*5+1]*w1 + u[j*5+2]*w2
                        + u[j*5+3]*w3 + u[j*5+4]*w4 + bb;
                pk.us[j] = f2bf(e);
            }
            const int mt = g >> 2;
            const int ll = lqc * 16 + ((g & 3) * 4 + lmh);
            Afrag[mt][s][ll] = pk.v;
        }
        __syncthreads();
    }

    float lpsum = 0.f;

    for (int it = 0; it < 4; ++it) {
        const int ns = (wave << 2) + it;   // wave's n-quarter, 64 n-cols per ns

        f32x4 acc[4][4];
        #pragma unroll
        for (int mt = 0; mt < 4; ++mt)
            #pragma unroll
            for (int t = 0; t < 4; ++t) acc[mt][t] = (f32x4){0.f, 0.f, 0.f, 0.f};

        #pragma unroll
        for (int s = 0; s < 8; ++s) {
            const short8 a0 = Afrag[0][s][l];
            const short8 a1 = Afrag[1][s][l];
            const short8 a2 = Afrag[2][s][l];
            const short8 a3 = Afrag[3][s][l];
            #pragma unroll
            for (int t = 0; t < 4; ++t) {
                const short8 bfr = Bf[(((ns * 4 + t) * 8 + s) << 6) + l];
                // swapped operands: bfr rows (n), A cols (m)
                acc[0][t] = __builtin_amdgcn_mfma_f32_16x16x32_bf16(bfr, a0, acc[0][t], 0, 0, 0);
                acc[1][t] = __builtin_amdgcn_mfma_f32_16x16x32_bf16(bfr, a1, acc[1][t], 0, 0, 0);
                acc[2][t] = __builtin_amdgcn_mfma_f32_16x16x32_bf16(bfr, a2, acc[2][t], 0, 0, 0);
                acc[3][t] = __builtin_amdgcn_mfma_f32_16x16x32_bf16(bfr, a3, acc[3][t], 0, 0, 0);
            }
        }

        // Epilogue: per mt-tile, dwordx4 R/C (n = ns*64 + t*16 + lq*4 + r, m fixed/lane)
        #pragma unroll
        for (int mt = 0; mt < 4; ++mt) {
            const size_t rb = (size_t)(m0 + mt * 16 + lm) * NTOP;
            #pragma unroll
            for (int t = 0; t < 4; ++t) {
                const int nst = (ns << 6) + (t << 4) + (lq << 2);
                if (nst < NTOP) {
                    const f32x4 rv = *reinterpret_cast<const f32x4*>(R + rb + nst);
                    const i32x4 cv = *reinterpret_cast<const i32x4*>(C + rb + nst);
                    #pragma unroll
                    for (int r = 0; r < 4; ++r) {
                        float muv = 1.f / (1.f + __expf(-acc[mt][t][r]));
                        float d   = rv[r] - muv;
                        float lp  = -50.f * d * d + 1.3836465597893728f;
                        if (cv[r] == 1) lpsum += lp;
                    }
                }
            }
        }
    }

    #pragma unroll
    for (int off = 32; off > 0; off >>= 1) lpsum += __shfl_down(lpsum, off);
    if (l == 0) atomicAdd(out, lpsum);
}

extern "C" void kernel_launch(void* const* d_in, const int* in_sizes, int n_in,
                              void* d_out, int out_size, void* d_ws, size_t ws_size,
                              hipStream_t stream) {
    const float* V     = (const float*)d_in[1];
    const float* R     = (const float*)d_in[2];
    const float* nw    = (const float*)d_in[3];
    const float* U     = (const float*)d_in[4];
    const float* w5    = (const float*)d_in[5];
    const float* b1    = (const float*)d_in[6];
    const float* noise = (const float*)d_in[7];
    const int*   C     = (const int*)d_in[8];
    float* out = (float*)d_out;

    // Workspace (known-safe 532,480 B footprint):
    //   colsum: [0, 4000)      (padded to 8192)
    //   Bp    : [8192, 532480) 1024*256*2 = 524288 B
    float*          colsum = (float*)d_ws;
    unsigned short* Bp     = (unsigned short*)((char*)d_ws + 8192);

    hipMemsetAsync(colsum, 0, NTOP * sizeof(float), stream);
    hipMemsetAsync(out, 0, sizeof(float), stream);
    hipLaunchKernelGGL(k_prep, dim3(4, 125), dim3(256), 0, stream, nw, colsum);
    hipLaunchKernelGGL(k_vj, dim3(128), dim3(256), 0, stream,
                       V, noise, colsum, Bp);
    hipLaunchKernelGGL(k_main, dim3(MROWS / MBLK), dim3(256), 0, stream,
                       U, w5, b1, (const short8*)Bp, R, C, out);
}

// Round 8
// 188.591 us; speedup vs baseline: 1.4780x; 1.1604x over previous
//
#include <hip/hip_runtime.h>
#include <hip/hip_bf16.h>

typedef __attribute__((ext_vector_type(8))) short short8;
typedef __attribute__((ext_vector_type(4))) float f32x4;
typedef __attribute__((ext_vector_type(4))) int   i32x4;

#define NTOP 1000
#define KC   256
#define MROWS 40000
#define MBLK  64

static __device__ __forceinline__ unsigned short f2bf(float x) {
    union { float f; unsigned u; } v; v.f = x;
    unsigned r = (v.u + 0x7FFFu + ((v.u >> 16) & 1u)) >> 16;
    return (unsigned short)r;
}

// Kernel 1: colsum[j] += sum over an 8-row slab of nw. colsum pre-zeroed by memset.
__global__ void k_prep(const float* __restrict__ nw,
                       float* __restrict__ colsum) {
    int j  = blockIdx.x * 256 + threadIdx.x;
    int i0 = blockIdx.y * 8;
    if (j < NTOP) {
        float s = 0.f;
        int iend = min(i0 + 8, NTOP);
        for (int i = i0; i < iend; ++i) s += nw[(size_t)i * NTOP + j];
        atomicAdd(colsum + j, s);
    }
}

// Kernel 2: build B' in MFMA-fragment order:
//   B'[((nt*8 + s)*64 + lane)] (short8) = V_j[n = nt*16 + (lane&15),
//                                             k = s*32 + (lane>>4)*8 + j]
__global__ void k_vj(const float* __restrict__ V,
                     const float* __restrict__ noise,
                     const float* __restrict__ colsum,
                     unsigned short* __restrict__ Bp) {
    int t  = blockIdx.x * 256 + threadIdx.x;   // 0 .. 64*8*64-1 = 32767
    int nt = t >> 9;
    int s  = (t >> 6) & 7;
    int l  = t & 63;
    int lm = l & 15, lq = l >> 4;
    int n  = nt * 16 + lm;
    int k0 = s * 32 + lq * 8;
    union { short8 v; unsigned short us[8]; } pk;
    if (n < NTOP) {
        float cs = colsum[n];
        #pragma unroll
        for (int j = 0; j < 8; ++j) {
            int idx = n * KC + k0 + j;
            pk.us[j] = f2bf(V[idx] * cs + 0.1f * noise[idx]);
        }
    } else {
        #pragma unroll
        for (int j = 0; j < 8; ++j) pk.us[j] = 0;
    }
    reinterpret_cast<short8*>(Bp)[t] = pk.v;
}

// Kernel 3: 64-row blocks, 4x B-reuse per Bf load (TCP line-request reduction),
// LOW-PRESSURE main loop: each wave sweeps 16 n-tiles one at a time with acc[4]
// (one f32x4 per m-tile). Peak live vector state ~90 VGPR -> no scratch spill
// (round-7 failure: acc[4][4]=64 VGPR + frags spilled 60MB to scratch).
// R/C prefetched one n-tile ahead in pinned issue slots (round-5 proven).
__global__ __launch_bounds__(256, 3) void k_main(
    const float* __restrict__ U, const float* __restrict__ w5,
    const float* __restrict__ b1, const short8* __restrict__ Bf,
    const float* __restrict__ R, const int* __restrict__ C,
    float* __restrict__ out)
{
    __shared__ short8 Afrag[4][8][64];   // [mt][s][ll] : 32 KB
    __shared__ float  rawU[5120];        // 4 U-rows    : 20 KB

    const int tid  = threadIdx.x;
    const int wave = tid >> 6;
    const int l    = tid & 63;
    const int lm = l & 15;       // output m within 16-tile (col = lane&15)
    const int lq = l >> 4;       // quad: n-subblock of 4 (row = lq*4 + r)
    const int m0 = blockIdx.x * MBLK;

    const float w0 = w5[0], w1 = w5[1], w2 = w5[2], w3 = w5[3], w4 = w5[4];
    const float bb = b1[0];

    // ---- A-build: 16 groups of 4 rows. Stage coalesced, compute from LDS. ----
    const float* ub = U + (size_t)m0 * (KC * 5);
    for (int g = 0; g < 16; ++g) {
        const float* src = ub + (size_t)g * 5120;
        #pragma unroll
        for (int j = 0; j < 5; ++j) {
            const int idx = j * 1024 + tid * 4;
            *reinterpret_cast<f32x4*>(&rawU[idx]) =
                *reinterpret_cast<const f32x4*>(src + idx);
        }
        __syncthreads();
        if (tid < 128) {   // 128 fragment-chunks for these 4 rows
            const int s   = tid >> 4;
            const int lqc = (tid >> 2) & 3;
            const int lmh = tid & 3;
            const int fi  = lmh * 1280 + s * 160 + lqc * 40;
            float u[40];
            #pragma unroll
            for (int i = 0; i < 10; ++i) {
                f32x4 t = *reinterpret_cast<const f32x4*>(&rawU[fi + i * 4]);
                u[i*4+0] = t.x; u[i*4+1] = t.y; u[i*4+2] = t.z; u[i*4+3] = t.w;
            }
            union { short8 v; unsigned short us[8]; } pk;
            #pragma unroll
            for (int j = 0; j < 8; ++j) {
                float e = u[j*5+0]*w0 + u[j*5+1]*w1 + u[j*5+2]*w2
                        + u[j*5+3]*w3 + u[j*5+4]*w4 + bb;
                pk.us[j] = f2bf(e);
            }
            const int mt = g >> 2;
            const int ll = lqc * 16 + ((g & 3) * 4 + lmh);
            Afrag[mt][s][ll] = pk.v;
        }
        __syncthreads();
    }

    // Per-lane fixed row bases (m = m0 + mt*16 + lm).
    const size_t rb0 = (size_t)(m0 +  0 + lm) * NTOP;
    const size_t rb1 = (size_t)(m0 + 16 + lm) * NTOP;
    const size_t rb2 = (size_t)(m0 + 32 + lm) * NTOP;
    const size_t rb3 = (size_t)(m0 + 48 + lm) * NTOP;

    // Load R/C dwordx4 for one 16-col n-tile, all 4 m-tiles (8 vector loads).
    auto LOADIT = [&](int nt16_, f32x4* rv_, i32x4* cv_) {
        const int nst = (nt16_ << 4) + (lq << 2);
        if (nst < NTOP) {
            rv_[0] = *reinterpret_cast<const f32x4*>(R + rb0 + nst);
            cv_[0] = *reinterpret_cast<const i32x4*>(C + rb0 + nst);
            rv_[1] = *reinterpret_cast<const f32x4*>(R + rb1 + nst);
            cv_[1] = *reinterpret_cast<const i32x4*>(C + rb1 + nst);
            rv_[2] = *reinterpret_cast<const f32x4*>(R + rb2 + nst);
            cv_[2] = *reinterpret_cast<const i32x4*>(C + rb2 + nst);
            rv_[3] = *reinterpret_cast<const f32x4*>(R + rb3 + nst);
            cv_[3] = *reinterpret_cast<const i32x4*>(C + rb3 + nst);
        } else {
            #pragma unroll
            for (int q = 0; q < 4; ++q) {
                rv_[q] = (f32x4){0.f, 0.f, 0.f, 0.f};
                cv_[q] = (i32x4){0, 0, 0, 0};
            }
        }
    };

    float lpsum = 0.f;
    const int nt0 = wave << 4;   // this wave's first 16-col n-tile

    f32x4 rv[4]; i32x4 cv[4];
    LOADIT(nt0, rv, cv);

    for (int it = 0; it < 16; ++it) {
        const int nt16 = nt0 + it;

        f32x4 acc[4];
        #pragma unroll
        for (int mt = 0; mt < 4; ++mt) acc[mt] = (f32x4){0.f, 0.f, 0.f, 0.f};

        #pragma unroll
        for (int s = 0; s < 8; ++s) {
            const short8 bfr = Bf[((nt16 * 8 + s) << 6) + l];
            const short8 a0 = Afrag[0][s][l];
            const short8 a1 = Afrag[1][s][l];
            const short8 a2 = Afrag[2][s][l];
            const short8 a3 = Afrag[3][s][l];
            // swapped operands: bfr rows (n), A cols (m). One Bf load -> 4 MFMAs.
            acc[0] = __builtin_amdgcn_mfma_f32_16x16x32_bf16(bfr, a0, acc[0], 0, 0, 0);
            acc[1] = __builtin_amdgcn_mfma_f32_16x16x32_bf16(bfr, a1, acc[1], 0, 0, 0);
            acc[2] = __builtin_amdgcn_mfma_f32_16x16x32_bf16(bfr, a2, acc[2], 0, 0, 0);
            acc[3] = __builtin_amdgcn_mfma_f32_16x16x32_bf16(bfr, a3, acc[3], 0, 0, 0);
        }

        f32x4 rv2[4]; i32x4 cv2[4];

        // ---- pinned issue slot: next n-tile's R/C (after this tile's Bf loads) ----
        __builtin_amdgcn_sched_barrier(0);
        if (it < 15) LOADIT(nt16 + 1, rv2, cv2);
        __builtin_amdgcn_sched_barrier(0);

        // Consume from registers: n = nt16*16 + lq*4 + r, m = m0 + mt*16 + lm.
        #pragma unroll
        for (int mt = 0; mt < 4; ++mt) {
            #pragma unroll
            for (int r = 0; r < 4; ++r) {
                float muv = 1.f / (1.f + __expf(-acc[mt][r]));
                float d   = rv[mt][r] - muv;
                float lp  = -50.f * d * d + 1.3836465597893728f;
                if (cv[mt][r] == 1) lpsum += lp;
            }
        }

        if (it < 15) {
            rv[0] = rv2[0]; cv[0] = cv2[0];
            rv[1] = rv2[1]; cv[1] = cv2[1];
            rv[2] = rv2[2]; cv[2] = cv2[2];
            rv[3] = rv2[3]; cv[3] = cv2[3];
        }
    }

    #pragma unroll
    for (int off = 32; off > 0; off >>= 1) lpsum += __shfl_down(lpsum, off);
    if (l == 0) atomicAdd(out, lpsum);
}

extern "C" void kernel_launch(void* const* d_in, const int* in_sizes, int n_in,
                              void* d_out, int out_size, void* d_ws, size_t ws_size,
                              hipStream_t stream) {
    const float* V     = (const float*)d_in[1];
    const float* R     = (const float*)d_in[2];
    const float* nw    = (const float*)d_in[3];
    const float* U     = (const float*)d_in[4];
    const float* w5    = (const float*)d_in[5];
    const float* b1    = (const float*)d_in[6];
    const float* noise = (const float*)d_in[7];
    const int*   C     = (const int*)d_in[8];
    float* out = (float*)d_out;

    // Workspace (known-safe 532,480 B footprint):
    //   colsum: [0, 4000)      (padded to 8192)
    //   Bp    : [8192, 532480) 1024*256*2 = 524288 B
    float*          colsum = (float*)d_ws;
    unsigned short* Bp     = (unsigned short*)((char*)d_ws + 8192);

    hipMemsetAsync(colsum, 0, NTOP * sizeof(float), stream);
    hipMemsetAsync(out, 0, sizeof(float), stream);
    hipLaunchKernelGGL(k_prep, dim3(4, 125), dim3(256), 0, stream, nw, colsum);
    hipLaunchKernelGGL(k_vj, dim3(128), dim3(256), 0, stream,
                       V, noise, colsum, Bp);
    hipLaunchKernelGGL(k_main, dim3(MROWS / MBLK), dim3(256), 0, stream,
                       U, w5, b1, (const short8*)Bp, R, C, out);
}